// Round 1
// baseline (2081.832 us; speedup 1.0000x reference)
//
#include <hip/hip_runtime.h>
#include <hip/hip_bf16.h>

// FastAttention (Performer / FAVOR+), fp32 baseline.
// B=4 H=16 L=4096 D_QK=64 D_V=64 M=256
#define BH_   64
#define Lq    4096
#define Dk    64
#define Dv    64
#define Mf    256
#define EP    68                       // padded buf1 row: 64 v-cols + 1 den + 3 pad (16B-aligned rows)
#define NORM  0.3535533905932738f      // 64^-0.25
#define INVSQRTM 0.0625f               // 1/sqrt(256)
#define EPSV  1e-6f

#define KCH 8
#define KB  (Lq / KCH)                 // 512 keys per block

// ---------------- Kernel 1: buf1[bh][m][e] = sum_k phi(k)[m] * c[k][e] ----------------
// grid (KCH, BH), 256 threads; thread t owns feature row m=t.
__global__ __launch_bounds__(256, 2)
void k1_build(const float* __restrict__ ks, const float* __restrict__ vs,
              const float* __restrict__ mask, const float* __restrict__ proj,
              float* __restrict__ buf1) {
  const int t  = threadIdx.x;
  const int bh = blockIdx.y;
  const int b  = bh >> 4;              // H = 16
  const int k0 = blockIdx.x * KB;

  __shared__ float2 hnp[KB];           // (half_sq_norm, mask * 1/sqrt(M)) per key

  // prologue: per-key hn and mask factor
  for (int kk = t; kk < KB; kk += 256) {
    const float4* kr = reinterpret_cast<const float4*>(ks + ((size_t)bh * Lq + (k0 + kk)) * Dk);
    float4 s4 = make_float4(0.f, 0.f, 0.f, 0.f);
#pragma unroll
    for (int j = 0; j < 16; ++j) {
      float4 kv = kr[j];
      s4.x += kv.x * kv.x; s4.y += kv.y * kv.y;
      s4.z += kv.z * kv.z; s4.w += kv.w * kv.w;
    }
    float hn = 0.5f * NORM * NORM * (s4.x + s4.y + s4.z + s4.w);
    float mk = mask[(size_t)b * Lq + (k0 + kk)];
    hnp[kk] = make_float2(hn, mk * INVSQRTM);
  }

  // thread's proj row (m = t), pre-scaled by NORM, held in 64 VGPRs
  float4 pr[16];
  {
    const float4* p4 = reinterpret_cast<const float4*>(proj + (size_t)t * Dk);
#pragma unroll
    for (int j = 0; j < 16; ++j) {
      float4 v = p4[j];
      pr[j] = make_float4(v.x * NORM, v.y * NORM, v.z * NORM, v.w * NORM);
    }
  }
  __syncthreads();

  float4 acc[16];
#pragma unroll
  for (int j = 0; j < 16; ++j) acc[j] = make_float4(0.f, 0.f, 0.f, 0.f);
  float den = 0.f;

  for (int kk = 0; kk < KB; ++kk) {
    const int k = k0 + kk;
    // key row: block-uniform address -> scalar/broadcast loads
    const float4* kr = reinterpret_cast<const float4*>(ks + ((size_t)bh * Lq + k) * Dk);
    float4 d4 = make_float4(0.f, 0.f, 0.f, 0.f);
#pragma unroll
    for (int j = 0; j < 16; ++j) {
      float4 kv = kr[j];
      d4.x += pr[j].x * kv.x; d4.y += pr[j].y * kv.y;
      d4.z += pr[j].z * kv.z; d4.w += pr[j].w * kv.w;
    }
    float2 hp = hnp[kk];
    float p = __expf((d4.x + d4.y + d4.z + d4.w) - hp.x) * hp.y;

    const float4* vr = reinterpret_cast<const float4*>(vs + ((size_t)bh * Lq + k) * Dv);
#pragma unroll
    for (int j = 0; j < 16; ++j) {
      float4 vv = vr[j];
      acc[j].x += p * vv.x; acc[j].y += p * vv.y;
      acc[j].z += p * vv.z; acc[j].w += p * vv.w;
    }
    den += p;
  }

  float* row = buf1 + ((size_t)bh * Mf + t) * EP;
#pragma unroll
  for (int j = 0; j < 16; ++j) {
    atomicAdd(row + 4 * j + 0, acc[j].x);
    atomicAdd(row + 4 * j + 1, acc[j].y);
    atomicAdd(row + 4 * j + 2, acc[j].z);
    atomicAdd(row + 4 * j + 3, acc[j].w);
  }
  atomicAdd(row + 64, den);
}

// ---------------- Kernel 2: ctx[q] = (phi(q) @ buf1)[:64] / clamp((phi(q) @ buf1)[64]) ----
// grid (QCH, BH), 256 threads; thread owns one query.
#define QCH 16
__global__ __launch_bounds__(256, 2)
void k2_ctx(const float* __restrict__ qs, const float* __restrict__ proj,
            const float* __restrict__ buf1, float* __restrict__ out) {
  const int t  = threadIdx.x;
  const int bh = blockIdx.y;
  const int q  = blockIdx.x * 256 + t;

  // query row scaled by NORM, in 64 VGPRs; half squared norm
  float4 xr[16];
  float hn;
  {
    const float4* qr = reinterpret_cast<const float4*>(qs + ((size_t)bh * Lq + q) * Dk);
    float4 s4 = make_float4(0.f, 0.f, 0.f, 0.f);
#pragma unroll
    for (int j = 0; j < 16; ++j) {
      float4 v = qr[j];
      xr[j] = make_float4(v.x * NORM, v.y * NORM, v.z * NORM, v.w * NORM);
      s4.x += xr[j].x * xr[j].x; s4.y += xr[j].y * xr[j].y;
      s4.z += xr[j].z * xr[j].z; s4.w += xr[j].w * xr[j].w;
    }
    hn = 0.5f * (s4.x + s4.y + s4.z + s4.w);
  }

  float4 acc[16];
#pragma unroll
  for (int j = 0; j < 16; ++j) acc[j] = make_float4(0.f, 0.f, 0.f, 0.f);
  float den = 0.f;

  const float4* b1 = reinterpret_cast<const float4*>(buf1 + (size_t)bh * Mf * EP);

  for (int m = 0; m < Mf; ++m) {
    // proj row m: uniform address -> scalar/broadcast loads
    const float4* pm = reinterpret_cast<const float4*>(proj + (size_t)m * Dk);
    float4 d4 = make_float4(0.f, 0.f, 0.f, 0.f);
#pragma unroll
    for (int j = 0; j < 16; ++j) {
      float4 pv = pm[j];
      d4.x += pv.x * xr[j].x; d4.y += pv.y * xr[j].y;
      d4.z += pv.z * xr[j].z; d4.w += pv.w * xr[j].w;
    }
    float p = __expf((d4.x + d4.y + d4.z + d4.w) - hn) * INVSQRTM;

    const float4* br = b1 + (size_t)m * (EP / 4);
#pragma unroll
    for (int j = 0; j < 16; ++j) {
      float4 bv = br[j];
      acc[j].x += p * bv.x; acc[j].y += p * bv.y;
      acc[j].z += p * bv.z; acc[j].w += p * bv.w;
    }
    den += p * br[16].x;               // e = 64 (ones column); pad (65..67) unused
  }

  den = (den < EPSV) ? EPSV : den;
  const float r = 1.0f / den;
  float4* orow = reinterpret_cast<float4*>(out + ((size_t)bh * Lq + q) * Dv);
#pragma unroll
  for (int j = 0; j < 16; ++j) {
    orow[j] = make_float4(acc[j].x * r, acc[j].y * r, acc[j].z * r, acc[j].w * r);
  }
}

extern "C" void kernel_launch(void* const* d_in, const int* in_sizes, int n_in,
                              void* d_out, int out_size, void* d_ws, size_t ws_size,
                              hipStream_t stream) {
  const float* qs   = (const float*)d_in[0];
  const float* ks   = (const float*)d_in[1];
  const float* vs   = (const float*)d_in[2];
  const float* mask = (const float*)d_in[3];
  const float* proj = (const float*)d_in[4];
  float* out  = (float*)d_out;
  float* buf1 = (float*)d_ws;          // BH * M * EP floats = 4.46 MB

  (void)in_sizes; (void)n_in; (void)out_size; (void)ws_size;

  hipMemsetAsync(buf1, 0, (size_t)BH_ * Mf * EP * sizeof(float), stream);

  dim3 g1(KCH, BH_), g2(QCH, BH_);
  k1_build<<<g1, 256, 0, stream>>>(ks, vs, mask, proj, buf1);
  k2_ctx<<<g2, 256, 0, stream>>>(qs, proj, buf1, out);
}

// Round 3
// 369.813 us; speedup vs baseline: 5.6294x; 5.6294x over previous
//
#include <hip/hip_runtime.h>
#include <hip/hip_bf16.h>

// FastAttention (Performer/FAVOR+) — bf16 MFMA, fixed NORM scaling + aligned LDS pitches.
// B=4 H=16 L=4096 D_QK=64 D_V=64 M=256
#define Lq    4096
#define NORM  0.3535533905932738f      // 64^-0.25  (applied to x ONLY)
#define SC    0.0625f                  // 1/sqrt(256)
#define EPSV  1e-6f

typedef short short8 __attribute__((ext_vector_type(8)));
typedef short short4v __attribute__((ext_vector_type(4)));
typedef float float4v __attribute__((ext_vector_type(4)));

#define MFMA16(a, b, c) __builtin_amdgcn_mfma_f32_16x16x32_bf16(a, b, c, 0, 0, 0)

__device__ __forceinline__ short f2bf(float f) {
  unsigned u = __builtin_bit_cast(unsigned, f);
  unsigned r = (u + 0x7FFFu + ((u >> 16) & 1u)) >> 16;
  return (short)r;
}

#define PITCH 80                       // shorts; 160 B rows -> every b128 frag read 16B-aligned

// ws layout: buf1 fp32 [64 bh][256 feat][80 e] (5.24 MB) then buf1T bf16 [64 bh][80 e][256 feat]
#define BUF1_FLOATS ((size_t)64 * 256 * 80)

// ---------------- Kernel 1: per (chunk, bh), 512 keys -> atomicAdd into buf1 fp32 ----------------
__global__ __launch_bounds__(256, 2)
void k1_build(const float* __restrict__ ks, const float* __restrict__ vs,
              const float* __restrict__ mask, const float* __restrict__ proj,
              float* __restrict__ buf1) {
  __shared__ short lx[64 * PITCH];     // [key][dim]
  __shared__ short lvT[80 * PITCH];    // [e][key]
  __shared__ short lphiT[256 * PITCH]; // [feat][key]
  __shared__ float lhnp[64 * 16];
  __shared__ float lhn[64];
  __shared__ float lmf[64];

  const int t    = threadIdx.x;
  const int w    = t >> 6;
  const int lane = t & 63;
  const int c    = lane & 15;
  const int quad = lane >> 4;
  const int chunk = blockIdx.x;
  const int bh    = blockIdx.y;
  const int bidx  = bh >> 4;           // H = 16

  // proj B-frags for feats w*64..+63 — UNSCALED (x carries the single NORM)
  short8 pf[4][2];
#pragma unroll
  for (int nt = 0; nt < 4; ++nt)
#pragma unroll
    for (int ks2 = 0; ks2 < 2; ++ks2) {
      const float4* p = reinterpret_cast<const float4*>(
          proj + ((size_t)(w * 64 + nt * 16 + c) * 64 + ks2 * 32 + quad * 8));
      float4 a = p[0], b = p[1];
      short8 f;
      f[0] = f2bf(a.x); f[1] = f2bf(a.y); f[2] = f2bf(a.z); f[3] = f2bf(a.w);
      f[4] = f2bf(b.x); f[5] = f2bf(b.y); f[6] = f2bf(b.z); f[7] = f2bf(b.w);
      pf[nt][ks2] = f;
    }

  // static vT rows 64..79: row 64 = ones, rows 65..79 = zeros
#pragma unroll
  for (int i = 0; i < 4; ++i) {
    int idx = i * 256 + t;
    int row = 64 + (idx >> 6), col = idx & 63;
    lvT[row * PITCH + col] = (row == 64) ? (short)0x3F80 : (short)0;
  }

  float4v acc[4][5];
#pragma unroll
  for (int mt = 0; mt < 4; ++mt)
#pragma unroll
    for (int nt = 0; nt < 5; ++nt) acc[mt][nt] = (float4v){0.f, 0.f, 0.f, 0.f};

  const float4* ks4 = reinterpret_cast<const float4*>(ks);
  const float4* vs4 = reinterpret_cast<const float4*>(vs);

  for (int kt = 0; kt < 8; ++kt) {
    const int k0g = chunk * 512 + kt * 64;
    __syncthreads();

    // stage keys (scaled by NORM) -> lx bf16; sumsq partials
#pragma unroll
    for (int i = 0; i < 4; ++i) {
      int f = i * 256 + t;
      int key = f >> 4, d4 = f & 15;
      float4 v = ks4[((size_t)bh * Lq + k0g + key) * 16 + d4];
      v.x *= NORM; v.y *= NORM; v.z *= NORM; v.w *= NORM;
      lhnp[key * 16 + d4] = v.x * v.x + v.y * v.y + v.z * v.z + v.w * v.w;
      short4v o; o[0] = f2bf(v.x); o[1] = f2bf(v.y); o[2] = f2bf(v.z); o[3] = f2bf(v.w);
      *reinterpret_cast<short4v*>(&lx[key * PITCH + d4 * 4]) = o;
    }
    // stage v transposed -> lvT[e][key]
#pragma unroll
    for (int i = 0; i < 4; ++i) {
      int f = i * 256 + t;
      int key = f >> 4, e4 = f & 15;
      float4 v = vs4[((size_t)bh * Lq + k0g + key) * 16 + e4];
      lvT[(e4 * 4 + 0) * PITCH + key] = f2bf(v.x);
      lvT[(e4 * 4 + 1) * PITCH + key] = f2bf(v.y);
      lvT[(e4 * 4 + 2) * PITCH + key] = f2bf(v.z);
      lvT[(e4 * 4 + 3) * PITCH + key] = f2bf(v.w);
    }
    __syncthreads();
    if (t < 64) {
      float s = 0.f;
#pragma unroll
      for (int j = 0; j < 16; ++j) s += lhnp[t * 16 + j];
      lhn[t] = 0.5f * s;
      lmf[t] = mask[(size_t)bidx * Lq + k0g + t] * SC;
    }
    __syncthreads();

    // phi MFMA: out[key][feat]; wave w covers feats w*64..+63
    float4v pacc[4][4];
#pragma unroll
    for (int mt = 0; mt < 4; ++mt)
#pragma unroll
      for (int nt = 0; nt < 4; ++nt) pacc[mt][nt] = (float4v){0.f, 0.f, 0.f, 0.f};
#pragma unroll
    for (int mt = 0; mt < 4; ++mt) {
      short8 a0 = *reinterpret_cast<short8*>(&lx[(mt * 16 + c) * PITCH + quad * 8]);
      short8 a1 = *reinterpret_cast<short8*>(&lx[(mt * 16 + c) * PITCH + 32 + quad * 8]);
#pragma unroll
      for (int nt = 0; nt < 4; ++nt) {
        pacc[mt][nt] = MFMA16(a0, pf[nt][0], pacc[mt][nt]);
        pacc[mt][nt] = MFMA16(a1, pf[nt][1], pacc[mt][nt]);
      }
    }
    // epilogue: p = exp(xproj - hn) * mask * SC -> bf16 -> lphiT[feat][key]
#pragma unroll
    for (int mt = 0; mt < 4; ++mt) {
      float4v hn4 = *reinterpret_cast<float4v*>(&lhn[mt * 16 + quad * 4]);
      float4v mf4 = *reinterpret_cast<float4v*>(&lmf[mt * 16 + quad * 4]);
#pragma unroll
      for (int nt = 0; nt < 4; ++nt) {
        short4v ph;
#pragma unroll
        for (int r = 0; r < 4; ++r)
          ph[r] = f2bf(__expf(pacc[mt][nt][r] - hn4[r]) * mf4[r]);
        *reinterpret_cast<short4v*>(
            &lphiT[(w * 64 + nt * 16 + c) * PITCH + mt * 16 + quad * 4]) = ph;
      }
    }
    __syncthreads();

    // buf1 accumulate: D[feat][e] += phiT @ c
    short8 bv[5][2];
#pragma unroll
    for (int nt = 0; nt < 5; ++nt) {
      bv[nt][0] = *reinterpret_cast<short8*>(&lvT[(nt * 16 + c) * PITCH + quad * 8]);
      bv[nt][1] = *reinterpret_cast<short8*>(&lvT[(nt * 16 + c) * PITCH + 32 + quad * 8]);
    }
#pragma unroll
    for (int mt = 0; mt < 4; ++mt) {
      short8 a0 = *reinterpret_cast<short8*>(&lphiT[(w * 64 + mt * 16 + c) * PITCH + quad * 8]);
      short8 a1 = *reinterpret_cast<short8*>(&lphiT[(w * 64 + mt * 16 + c) * PITCH + 32 + quad * 8]);
#pragma unroll
      for (int nt = 0; nt < 5; ++nt) {
        acc[mt][nt] = MFMA16(a0, bv[nt][0], acc[mt][nt]);
        acc[mt][nt] = MFMA16(a1, bv[nt][1], acc[mt][nt]);
      }
    }
  }

  // atomic accumulate into buf1 fp32 (8-way contention across chunks)
  float* bp = buf1 + (size_t)bh * 256 * 80;
#pragma unroll
  for (int mt = 0; mt < 4; ++mt)
#pragma unroll
    for (int nt = 0; nt < 5; ++nt)
#pragma unroll
      for (int r = 0; r < 4; ++r) {
        int feat = w * 64 + mt * 16 + quad * 4 + r;
        int e    = nt * 16 + c;
        atomicAdd(bp + (size_t)feat * 80 + e, acc[mt][nt][r]);
      }
}

// ---------------- Kernel 1.5: transpose + bf16: buf1T[bh][e][feat] ----------------
__global__ __launch_bounds__(256, 4)
void k1_reduce(const float* __restrict__ buf1, short* __restrict__ buf1T) {
  const int bh = blockIdx.x;
  const int t  = threadIdx.x;
  for (int j = 0; j < 80; ++j) {
    int idx = j * 256 + t;            // over [feat][e] (20480)
    int feat = idx / 80, e = idx % 80;
    buf1T[(size_t)bh * 20480 + e * 256 + feat] = f2bf(buf1[(size_t)bh * 20480 + idx]);
  }
}

// ---------------- Kernel 2: per (qchunk, bh), 64 q rows -> ctx ----------------
__global__ __launch_bounds__(256, 2)
void k2_ctx(const float* __restrict__ qs, const float* __restrict__ proj,
            const short* __restrict__ buf1T, float* __restrict__ out) {
  __shared__ short lq[64 * PITCH];    // [q][dim]
  __shared__ short lphi[64 * 264];    // [q][feat] pitch 264 (528 B rows, 16B-aligned)
  __shared__ float lhnp[64 * 16];
  __shared__ float lhn[64];

  const int t    = threadIdx.x;
  const int w    = t >> 6;
  const int lane = t & 63;
  const int c    = lane & 15;
  const int quad = lane >> 4;
  const int q0   = blockIdx.x * 64;
  const int bh   = blockIdx.y;

  // proj B-frags — UNSCALED
  short8 pf[4][2];
#pragma unroll
  for (int nt = 0; nt < 4; ++nt)
#pragma unroll
    for (int ks2 = 0; ks2 < 2; ++ks2) {
      const float4* p = reinterpret_cast<const float4*>(
          proj + ((size_t)(w * 64 + nt * 16 + c) * 64 + ks2 * 32 + quad * 8));
      float4 a = p[0], b = p[1];
      short8 f;
      f[0] = f2bf(a.x); f[1] = f2bf(a.y); f[2] = f2bf(a.z); f[3] = f2bf(a.w);
      f[4] = f2bf(b.x); f[5] = f2bf(b.y); f[6] = f2bf(b.z); f[7] = f2bf(b.w);
      pf[nt][ks2] = f;
    }

  const float4* qs4 = reinterpret_cast<const float4*>(qs);
#pragma unroll
  for (int i = 0; i < 4; ++i) {
    int f = i * 256 + t;
    int q = f >> 4, d4 = f & 15;
    float4 v = qs4[((size_t)bh * Lq + q0 + q) * 16 + d4];
    v.x *= NORM; v.y *= NORM; v.z *= NORM; v.w *= NORM;
    lhnp[q * 16 + d4] = v.x * v.x + v.y * v.y + v.z * v.z + v.w * v.w;
    short4v o; o[0] = f2bf(v.x); o[1] = f2bf(v.y); o[2] = f2bf(v.z); o[3] = f2bf(v.w);
    *reinterpret_cast<short4v*>(&lq[q * PITCH + d4 * 4]) = o;
  }
  __syncthreads();
  if (t < 64) {
    float s = 0.f;
#pragma unroll
    for (int j = 0; j < 16; ++j) s += lhnp[t * 16 + j];
    lhn[t] = 0.5f * s;
  }
  __syncthreads();

  // phi_q MFMA: out[q][feat]
  float4v pacc[4][4];
#pragma unroll
  for (int mt = 0; mt < 4; ++mt)
#pragma unroll
    for (int nt = 0; nt < 4; ++nt) pacc[mt][nt] = (float4v){0.f, 0.f, 0.f, 0.f};
#pragma unroll
  for (int mt = 0; mt < 4; ++mt) {
    short8 a0 = *reinterpret_cast<short8*>(&lq[(mt * 16 + c) * PITCH + quad * 8]);
    short8 a1 = *reinterpret_cast<short8*>(&lq[(mt * 16 + c) * PITCH + 32 + quad * 8]);
#pragma unroll
    for (int nt = 0; nt < 4; ++nt) {
      pacc[mt][nt] = MFMA16(a0, pf[nt][0], pacc[mt][nt]);
      pacc[mt][nt] = MFMA16(a1, pf[nt][1], pacc[mt][nt]);
    }
  }
#pragma unroll
  for (int mt = 0; mt < 4; ++mt) {
    float4v hn4 = *reinterpret_cast<float4v*>(&lhn[mt * 16 + quad * 4]);
#pragma unroll
    for (int nt = 0; nt < 4; ++nt) {
#pragma unroll
      for (int r = 0; r < 4; ++r) {
        int q = mt * 16 + quad * 4 + r;
        lphi[q * 264 + w * 64 + nt * 16 + c] =
            f2bf(__expf(pacc[mt][nt][r] - hn4[r]) * SC);
      }
    }
  }
  __syncthreads();

  // ctx MFMA: D[q][e] = phi_q @ buf1 ; wave w: q rows w*16..+15
  float4v cacc[5];
#pragma unroll
  for (int nt = 0; nt < 5; ++nt) cacc[nt] = (float4v){0.f, 0.f, 0.f, 0.f};
  const short* bT = buf1T + (size_t)bh * 20480;
#pragma unroll
  for (int ks2 = 0; ks2 < 8; ++ks2) {
    short8 a = *reinterpret_cast<short8*>(&lphi[(w * 16 + c) * 264 + ks2 * 32 + quad * 8]);
#pragma unroll
    for (int nt = 0; nt < 5; ++nt) {
      short8 b = *reinterpret_cast<const short8*>(
          &bT[(nt * 16 + c) * 256 + ks2 * 32 + quad * 8]);
      cacc[nt] = MFMA16(a, b, cacc[nt]);
    }
  }

  // den = col e=64 -> frag nt=4, lanes with c==0 (lane = quad*16)
  float rinv[4];
#pragma unroll
  for (int r = 0; r < 4; ++r) {
    float den = __shfl(cacc[4][r], (lane & 48));
    den = fmaxf(den, EPSV);
    rinv[r] = 1.0f / den;
  }
#pragma unroll
  for (int nt = 0; nt < 4; ++nt)
#pragma unroll
    for (int r = 0; r < 4; ++r) {
      int q = q0 + w * 16 + quad * 4 + r;
      out[((size_t)bh * Lq + q) * 64 + nt * 16 + c] = cacc[nt][r] * rinv[r];
    }
}

extern "C" void kernel_launch(void* const* d_in, const int* in_sizes, int n_in,
                              void* d_out, int out_size, void* d_ws, size_t ws_size,
                              hipStream_t stream) {
  const float* qs   = (const float*)d_in[0];
  const float* ks   = (const float*)d_in[1];
  const float* vs   = (const float*)d_in[2];
  const float* mask = (const float*)d_in[3];
  const float* proj = (const float*)d_in[4];
  float* out = (float*)d_out;
  float* buf1 = (float*)d_ws;
  short* buf1T = (short*)((char*)d_ws + BUF1_FLOATS * sizeof(float));

  (void)in_sizes; (void)n_in; (void)out_size; (void)ws_size;

  hipMemsetAsync(buf1, 0, BUF1_FLOATS * sizeof(float), stream);
  k1_build<<<dim3(8, 64), 256, 0, stream>>>(ks, vs, mask, proj, buf1);
  k1_reduce<<<dim3(64), 256, 0, stream>>>(buf1, buf1T);
  k2_ctx<<<dim3(64, 64), 256, 0, stream>>>(qs, proj, buf1T, out);
}

// Round 4
// 368.230 us; speedup vs baseline: 5.6536x; 1.0043x over previous
//
#include <hip/hip_runtime.h>
#include <hip/hip_bf16.h>

// FastAttention (Performer/FAVOR+) — bf16 MFMA, latency-optimized.
// B=4 H=16 L=4096 D_QK=64 D_V=64 M=256
#define Lq    4096
#define NORM  0.3535533905932738f      // 64^-0.25 (applied to x only)
#define SC    0.0625f                  // 1/sqrt(256)
#define EPSV  1e-6f

typedef short short8 __attribute__((ext_vector_type(8)));
typedef short short4v __attribute__((ext_vector_type(4)));
typedef float float4v __attribute__((ext_vector_type(4)));

#define MFMA16(a, b, c) __builtin_amdgcn_mfma_f32_16x16x32_bf16(a, b, c, 0, 0, 0)

__device__ __forceinline__ short f2bf(float f) {
  unsigned u = __builtin_bit_cast(unsigned, f);
  unsigned r = (u + 0x7FFFu + ((u >> 16) & 1u)) >> 16;
  return (short)r;
}

#define PITCH 80                       // k1 LDS pitch (shorts): 160 B rows, b128-aligned
#define P2    268                      // k2 lphi pitch: 536 B = 134 dw = 6 banks/row -> conflict-free

// ws layout (256B-aligned): buf1 fp32 [64][256][80], buf1T bf16 [64][80][256], projb bf16 [256][64]
#define BUF1_FLOATS ((size_t)64 * 256 * 80)
#define BUF1T_OFF   (BUF1_FLOATS * 4)                    // 5,242,880
#define PROJB_OFF   (BUF1T_OFF + (size_t)64 * 20480 * 2) // +2,621,440

// ---------------- Kernel 0: proj fp32 -> bf16 (one-time, 32 KB) ----------------
__global__ __launch_bounds__(256)
void k0_proj(const float* __restrict__ proj, short* __restrict__ projb) {
  int i = (blockIdx.x * 256 + threadIdx.x) * 4;          // 16 blocks cover 16384
  float4 v = *reinterpret_cast<const float4*>(proj + i);
  short4v o; o[0] = f2bf(v.x); o[1] = f2bf(v.y); o[2] = f2bf(v.z); o[3] = f2bf(v.w);
  *reinterpret_cast<short4v*>(projb + i) = o;
}

// ---------------- Kernel 1: per (chunk, bh), 512 keys -> atomicAdd buf1 fp32 ----------------
__global__ __launch_bounds__(256, 2)
void k1_build(const float* __restrict__ ks, const float* __restrict__ vs,
              const float* __restrict__ mask, const short* __restrict__ projb,
              float* __restrict__ buf1) {
  __shared__ short lx[64 * PITCH];     // [key][dim]
  __shared__ short lvT[80 * PITCH];    // [e][key]
  __shared__ short lphiT[256 * PITCH]; // [feat][key] — wave-private 64-row bands
  __shared__ float lhnp[64 * 16];
  __shared__ float lhn[64];
  __shared__ float lmfAll[512];

  const int t    = threadIdx.x;
  const int w    = t >> 6;
  const int lane = t & 63;
  const int c    = lane & 15;
  const int quad = lane >> 4;
  const int chunk = blockIdx.x;
  const int bh    = blockIdx.y;
  const int bidx  = bh >> 4;           // H = 16

  // one-time: mask for this block's 512 keys
  for (int i = t; i < 512; i += 256)
    lmfAll[i] = mask[(size_t)bidx * Lq + chunk * 512 + i] * SC;

  // proj B-frags for feats w*64..+63 (bf16, single b128 loads)
  short8 pf[4][2];
#pragma unroll
  for (int nt = 0; nt < 4; ++nt)
#pragma unroll
    for (int h = 0; h < 2; ++h)
      pf[nt][h] = *reinterpret_cast<const short8*>(
          &projb[(size_t)(w * 64 + nt * 16 + c) * 64 + h * 32 + quad * 8]);

  // static lvT rows 64..79: row 64 = ones, rows 65..79 = zeros
#pragma unroll
  for (int i = 0; i < 4; ++i) {
    int idx = i * 256 + t;
    int row = 64 + (idx >> 6), col = idx & 63;
    lvT[row * PITCH + col] = (row == 64) ? (short)0x3F80 : (short)0;
  }

  float4v acc[4][5];
#pragma unroll
  for (int mt = 0; mt < 4; ++mt)
#pragma unroll
    for (int nt = 0; nt < 5; ++nt) acc[mt][nt] = (float4v){0.f, 0.f, 0.f, 0.f};

  const float4* ks4 = reinterpret_cast<const float4*>(ks);
  const float4* vs4 = reinterpret_cast<const float4*>(vs);
  const int key0 = (t >> 4);           // staging: f = i*256+t -> key = i*16 + t/16, d4 = t&15
  const int d4   = t & 15;

  // prefetch tile 0
  float4 kx[4], vx[4];
#pragma unroll
  for (int i = 0; i < 4; ++i) {
    size_t base = ((size_t)bh * Lq + chunk * 512 + (i * 16 + key0)) * 16 + d4;
    kx[i] = ks4[base]; vx[i] = vs4[base];
  }

  for (int kt = 0; kt < 8; ++kt) {
    __syncthreads();                   // (a) prev iter's LDS readers done

    // regs -> LDS (scale, sumsq, cvt, v-transpose)
#pragma unroll
    for (int i = 0; i < 4; ++i) {
      int key = i * 16 + key0;
      float4 v = kx[i];
      v.x *= NORM; v.y *= NORM; v.z *= NORM; v.w *= NORM;
      lhnp[key * 16 + d4] = v.x * v.x + v.y * v.y + v.z * v.z + v.w * v.w;
      short4v o; o[0] = f2bf(v.x); o[1] = f2bf(v.y); o[2] = f2bf(v.z); o[3] = f2bf(v.w);
      *reinterpret_cast<short4v*>(&lx[key * PITCH + d4 * 4]) = o;
      float4 u = vx[i];
      lvT[(d4 * 4 + 0) * PITCH + key] = f2bf(u.x);
      lvT[(d4 * 4 + 1) * PITCH + key] = f2bf(u.y);
      lvT[(d4 * 4 + 2) * PITCH + key] = f2bf(u.z);
      lvT[(d4 * 4 + 3) * PITCH + key] = f2bf(u.w);
    }
    __syncthreads();                   // (b) staging visible

    // prefetch next tile (in flight during MFMA work)
    if (kt + 1 < 8) {
#pragma unroll
      for (int i = 0; i < 4; ++i) {
        size_t base = ((size_t)bh * Lq + chunk * 512 + (kt + 1) * 64 + (i * 16 + key0)) * 16 + d4;
        kx[i] = ks4[base]; vx[i] = vs4[base];
      }
    }
    if (t < 64) {
      float s = 0.f;
#pragma unroll
      for (int j = 0; j < 16; ++j) s += lhnp[t * 16 + j];
      lhn[t] = 0.5f * s;
    }
    __syncthreads();                   // (c) lhn ready

    // per key-subtile: phi MFMA -> exp -> wave-private lphiT
#pragma unroll
    for (int mt = 0; mt < 4; ++mt) {
      short8 a0 = *reinterpret_cast<short8*>(&lx[(mt * 16 + c) * PITCH + quad * 8]);
      short8 a1 = *reinterpret_cast<short8*>(&lx[(mt * 16 + c) * PITCH + 32 + quad * 8]);
      float4v hn4 = *reinterpret_cast<float4v*>(&lhn[mt * 16 + quad * 4]);
      float4v mf4 = *reinterpret_cast<float4v*>(&lmfAll[kt * 64 + mt * 16 + quad * 4]);
#pragma unroll
      for (int nt = 0; nt < 4; ++nt) {
        float4v p = (float4v){0.f, 0.f, 0.f, 0.f};
        p = MFMA16(a0, pf[nt][0], p);
        p = MFMA16(a1, pf[nt][1], p);
        short4v ph;
#pragma unroll
        for (int r = 0; r < 4; ++r)
          ph[r] = f2bf(__expf(p[r] - hn4[r]) * mf4[r]);
        *reinterpret_cast<short4v*>(
            &lphiT[(w * 64 + nt * 16 + c) * PITCH + mt * 16 + quad * 4]) = ph;
      }
    }
    // no barrier: lphiT band is wave-private; within-wave DS ordering suffices

    // acc MFMA: D[feat][e] += phiT @ [v | 1]
    short8 bv[5][2];
#pragma unroll
    for (int nt = 0; nt < 5; ++nt) {
      bv[nt][0] = *reinterpret_cast<short8*>(&lvT[(nt * 16 + c) * PITCH + quad * 8]);
      bv[nt][1] = *reinterpret_cast<short8*>(&lvT[(nt * 16 + c) * PITCH + 32 + quad * 8]);
    }
#pragma unroll
    for (int mt = 0; mt < 4; ++mt) {
      short8 a0 = *reinterpret_cast<short8*>(&lphiT[(w * 64 + mt * 16 + c) * PITCH + quad * 8]);
      short8 a1 = *reinterpret_cast<short8*>(&lphiT[(w * 64 + mt * 16 + c) * PITCH + 32 + quad * 8]);
#pragma unroll
      for (int nt = 0; nt < 5; ++nt) {
        acc[mt][nt] = MFMA16(a0, bv[nt][0], acc[mt][nt]);
        acc[mt][nt] = MFMA16(a1, bv[nt][1], acc[mt][nt]);
      }
    }
  }

  float* bp = buf1 + (size_t)bh * 256 * 80;
#pragma unroll
  for (int mt = 0; mt < 4; ++mt)
#pragma unroll
    for (int nt = 0; nt < 5; ++nt)
#pragma unroll
      for (int r = 0; r < 4; ++r) {
        int feat = w * 64 + mt * 16 + quad * 4 + r;
        int e    = nt * 16 + c;
        atomicAdd(bp + (size_t)feat * 80 + e, acc[mt][nt][r]);
      }
}

// ---------------- Kernel 1.5: transpose + cvt: buf1T[bh][e][feat] bf16 ----------------
__global__ __launch_bounds__(256, 8)
void k1_reduce(const float* __restrict__ buf1, short* __restrict__ buf1T) {
  const int bh = blockIdx.x;
  const int s  = blockIdx.y;           // 8 segments
  const int t  = threadIdx.x;
#pragma unroll
  for (int j = 0; j < 10; ++j) {
    int idx = s * 2560 + j * 256 + t;  // over e*256+feat
    int e = idx >> 8, feat = idx & 255;
    buf1T[(size_t)bh * 20480 + idx] = f2bf(buf1[(size_t)bh * 20480 + feat * 80 + e]);
  }
}

// ---------------- Kernel 2: barrier-free; wave owns 16 q rows ----------------
__global__ __launch_bounds__(256, 4)
void k2_ctx(const float* __restrict__ qs, const short* __restrict__ projb,
            const short* __restrict__ buf1T, float* __restrict__ out) {
  __shared__ short lphi[64 * P2];      // [q(local)][feat] — wave-private 16-row bands
  __shared__ float lhnw[64];           // per-wave hn slots

  const int t    = threadIdx.x;
  const int w    = t >> 6;
  const int lane = t & 63;
  const int c    = lane & 15;
  const int quad = lane >> 4;
  const int q0   = blockIdx.x * 64;
  const int bh   = blockIdx.y;

  // lane's q row: q0 + w*16 + c; dims quad*8..+7 and 32+quad*8..+7
  const float* qrow = qs + ((size_t)bh * Lq + q0 + w * 16 + c) * 64;
  float4 v0 = *reinterpret_cast<const float4*>(qrow + quad * 8);
  float4 v1 = *reinterpret_cast<const float4*>(qrow + quad * 8 + 4);
  float4 v2 = *reinterpret_cast<const float4*>(qrow + 32 + quad * 8);
  float4 v3 = *reinterpret_cast<const float4*>(qrow + 32 + quad * 8 + 4);
  v0.x *= NORM; v0.y *= NORM; v0.z *= NORM; v0.w *= NORM;
  v1.x *= NORM; v1.y *= NORM; v1.z *= NORM; v1.w *= NORM;
  v2.x *= NORM; v2.y *= NORM; v2.z *= NORM; v2.w *= NORM;
  v3.x *= NORM; v3.y *= NORM; v3.z *= NORM; v3.w *= NORM;

  float s = v0.x * v0.x + v0.y * v0.y + v0.z * v0.z + v0.w * v0.w
          + v1.x * v1.x + v1.y * v1.y + v1.z * v1.z + v1.w * v1.w
          + v2.x * v2.x + v2.y * v2.y + v2.z * v2.z + v2.w * v2.w
          + v3.x * v3.x + v3.y * v3.y + v3.z * v3.z + v3.w * v3.w;
  s += __shfl_xor(s, 16);
  s += __shfl_xor(s, 32);              // full |x*NORM|^2 for row c
  if (quad == 0) lhnw[w * 16 + c] = 0.5f * s;

  short8 qa0, qa1;
  qa0[0] = f2bf(v0.x); qa0[1] = f2bf(v0.y); qa0[2] = f2bf(v0.z); qa0[3] = f2bf(v0.w);
  qa0[4] = f2bf(v1.x); qa0[5] = f2bf(v1.y); qa0[6] = f2bf(v1.z); qa0[7] = f2bf(v1.w);
  qa1[0] = f2bf(v2.x); qa1[1] = f2bf(v2.y); qa1[2] = f2bf(v2.z); qa1[3] = f2bf(v2.w);
  qa1[4] = f2bf(v3.x); qa1[5] = f2bf(v3.y); qa1[6] = f2bf(v3.z); qa1[7] = f2bf(v3.w);

  // hn for epilogue rows quad*4+r (within-wave LDS ordering, no barrier)
  float4v hn4 = *reinterpret_cast<float4v*>(&lhnw[w * 16 + quad * 4]);

  // phi: 16 n-tiles of 16 feats; exp; transpose into wave-private lphi band
#pragma unroll
  for (int nt = 0; nt < 16; ++nt) {
    short8 b0 = *reinterpret_cast<const short8*>(&projb[(size_t)(nt * 16 + c) * 64 + quad * 8]);
    short8 b1 = *reinterpret_cast<const short8*>(&projb[(size_t)(nt * 16 + c) * 64 + 32 + quad * 8]);
    float4v p = (float4v){0.f, 0.f, 0.f, 0.f};
    p = MFMA16(qa0, b0, p);
    p = MFMA16(qa1, b1, p);
#pragma unroll
    for (int r = 0; r < 4; ++r)
      lphi[(w * 16 + quad * 4 + r) * P2 + nt * 16 + c] =
          f2bf(__expf(p[r] - hn4[r]) * SC);
  }

  // ctx: D[q][e] = phi @ buf1T^T ; A from own lphi band, B from L2-hot buf1T
  float4v cacc[5];
#pragma unroll
  for (int nt = 0; nt < 5; ++nt) cacc[nt] = (float4v){0.f, 0.f, 0.f, 0.f};
  const short* bT = buf1T + (size_t)bh * 20480;
#pragma unroll
  for (int k2i = 0; k2i < 8; ++k2i) {
    short8 a = *reinterpret_cast<short8*>(&lphi[(w * 16 + c) * P2 + k2i * 32 + quad * 8]);
#pragma unroll
    for (int nt = 0; nt < 5; ++nt) {
      short8 b = *reinterpret_cast<const short8*>(&bT[(nt * 16 + c) * 256 + k2i * 32 + quad * 8]);
      cacc[nt] = MFMA16(a, b, cacc[nt]);
    }
  }

  // den = col e=64 (frag nt=4, lanes c==0); broadcast within row group
  float rinv[4];
#pragma unroll
  for (int r = 0; r < 4; ++r) {
    float den = __shfl(cacc[4][r], (lane & 48));
    den = fmaxf(den, EPSV);
    rinv[r] = 1.0f / den;
  }
#pragma unroll
  for (int nt = 0; nt < 4; ++nt)
#pragma unroll
    for (int r = 0; r < 4; ++r) {
      int q = q0 + w * 16 + quad * 4 + r;
      out[((size_t)bh * Lq + q) * 64 + nt * 16 + c] = cacc[nt][r] * rinv[r];
    }
}

extern "C" void kernel_launch(void* const* d_in, const int* in_sizes, int n_in,
                              void* d_out, int out_size, void* d_ws, size_t ws_size,
                              hipStream_t stream) {
  const float* qs   = (const float*)d_in[0];
  const float* ks   = (const float*)d_in[1];
  const float* vs   = (const float*)d_in[2];
  const float* mask = (const float*)d_in[3];
  const float* proj = (const float*)d_in[4];
  float* out  = (float*)d_out;
  float* buf1 = (float*)d_ws;
  short* buf1T = (short*)((char*)d_ws + BUF1T_OFF);
  short* projb = (short*)((char*)d_ws + PROJB_OFF);

  (void)in_sizes; (void)n_in; (void)out_size; (void)ws_size;

  hipMemsetAsync(buf1, 0, BUF1_FLOATS * sizeof(float), stream);
  k0_proj<<<dim3(16), 256, 0, stream>>>(proj, projb);
  k1_build<<<dim3(8, 64), 256, 0, stream>>>(ks, vs, mask, projb, buf1);
  k1_reduce<<<dim3(64, 8), 256, 0, stream>>>(buf1, buf1T);
  k2_ctx<<<dim3(64, 64), 256, 0, stream>>>(qs, projb, buf1T, out);
}